// Round 2
// baseline (101.242 us; speedup 1.0000x reference)
//
#include <hip/hip_runtime.h>

#define CHUNK 1024
#define QB 4  // fallback: queries per block

// ---------------------------------------------------------------------------
// Fast path, kernel 1: one query per LANE, points streamed through SGPRs.
// Wave w handles queries [qw*64, qw*64+64) against point chunk ck.
// Writes packed (dist_bits<<32 | global_idx) u64 partial per query.
// Exact numpy argmin semantics: strict < ascending within each chain keeps
// the first index; u64 lexicographic min across chains/chunks keeps the
// smallest index among equal distances (dist >= 0 so f32 bits are monotone).
// ---------------------------------------------------------------------------
__global__ __launch_bounds__(256, 4)
void nn_part_kernel(const float* __restrict__ x,
                    const float* __restrict__ pts,
                    unsigned long long* __restrict__ part, // [nchunk][B]
                    int B, int qw_shift)
{
    const int lane = threadIdx.x & 63;
    // readfirstlane is load-bearing: it makes the wave id (and thus the point
    // chunk pointer) provably uniform so point loads compile to s_load_*.
    const int wv = __builtin_amdgcn_readfirstlane((int)(threadIdx.x >> 6));
    const int w  = blockIdx.x * 4 + wv;
    const int qw = w & ((1 << qw_shift) - 1);   // query-wave index (B/64 is pow2)
    const int ck = w >> qw_shift;               // point-chunk index

    const int q = (qw << 6) + lane;
    const float xq = x[q];

    const float* __restrict__ pc = pts + (size_t)ck * CHUNK;  // uniform

    const float inf = __builtin_inff();
    float bd0 = inf, bd1 = inf, bd2 = inf, bd3 = inf;
    int bj0 = 0, bj1 = 1, bj2 = 2, bj3 = 3;

    #pragma unroll 8
    for (int g = 0; g < CHUNK / 4; ++g) {
        // uniform scalar loads (constant cache), zero vector-memory traffic
        float p0 = pc[4 * g + 0];
        float p1 = pc[4 * g + 1];
        float p2 = pc[4 * g + 2];
        float p3 = pc[4 * g + 3];
        float d0 = fabsf(p0 - xq);
        float d1 = fabsf(p1 - xq);
        float d2 = fabsf(p2 - xq);
        float d3 = fabsf(p3 - xq);
        if (d0 < bd0) { bd0 = d0; bj0 = 4 * g + 0; }
        if (d1 < bd1) { bd1 = d1; bj1 = 4 * g + 1; }
        if (d2 < bd2) { bd2 = d2; bj2 = 4 * g + 2; }
        if (d3 < bd3) { bd3 = d3; bj3 = 4 * g + 3; }
    }

    const unsigned base = (unsigned)ck * (unsigned)CHUNK;
    unsigned long long k0 = ((unsigned long long)__float_as_uint(bd0) << 32) | (base + (unsigned)bj0);
    unsigned long long k1 = ((unsigned long long)__float_as_uint(bd1) << 32) | (base + (unsigned)bj1);
    unsigned long long k2 = ((unsigned long long)__float_as_uint(bd2) << 32) | (base + (unsigned)bj2);
    unsigned long long k3 = ((unsigned long long)__float_as_uint(bd3) << 32) | (base + (unsigned)bj3);
    unsigned long long ka = k0 < k1 ? k0 : k1;
    unsigned long long kb = k2 < k3 ? k2 : k3;
    unsigned long long key = ka < kb ? ka : kb;

    part[(size_t)ck * B + q] = key;   // lane-contiguous -> coalesced
}

// ---------------------------------------------------------------------------
// Fast path, kernel 2: one wave per query reduces nchunk partials, gathers acc.
// ---------------------------------------------------------------------------
__global__ __launch_bounds__(256, 4)
void nn_reduce_kernel(const unsigned long long* __restrict__ part,
                      const float* __restrict__ acc,
                      float* __restrict__ out,
                      int B, int nchunk)
{
    const int lane = threadIdx.x & 63;
    const int wv   = threadIdx.x >> 6;
    const int q    = blockIdx.x * 4 + wv;
    if (q >= B) return;

    unsigned long long key = ~0ULL;
    for (int c = lane; c < nchunk; c += 64) {
        unsigned long long k = part[(size_t)c * B + q];
        key = k < key ? k : key;
    }
    #pragma unroll
    for (int off = 1; off < 64; off <<= 1) {
        unsigned long long o = __shfl_xor(key, off, 64);
        key = key < o ? key : o;
    }
    if (lane == 0) {
        out[q] = acc[(unsigned)(key & 0xffffffffULL)];
    }
}

// ---------------------------------------------------------------------------
// Fallback (round-1 kernel): one query per wave, vector loads.
// ---------------------------------------------------------------------------
__global__ __launch_bounds__(256, 4)
void nn_kernel(const float* __restrict__ x,
               const float* __restrict__ pts,
               const float* __restrict__ acc,
               float* __restrict__ out,
               int B, int N) {
    const int lane = threadIdx.x & 63;
    const int wave = threadIdx.x >> 6;
    const int q    = blockIdx.x * QB + wave;
    if (q >= B) return;

    const float xq = x[q];
    const int G = N >> 2;
    const int J = G >> 6;

    float bd0 = __builtin_inff(), bd1 = __builtin_inff(),
          bd2 = __builtin_inff(), bd3 = __builtin_inff();
    int   bj0 = 0, bj1 = 0, bj2 = 0, bj3 = 0;

    const float4* __restrict__ p4 = reinterpret_cast<const float4*>(pts);

    #pragma unroll 4
    for (int j = 0; j < J; ++j) {
        float4 v = p4[lane + 64 * j];
        float d0 = fabsf(v.x - xq);
        float d1 = fabsf(v.y - xq);
        float d2 = fabsf(v.z - xq);
        float d3 = fabsf(v.w - xq);
        if (d0 < bd0) { bd0 = d0; bj0 = j; }
        if (d1 < bd1) { bd1 = d1; bj1 = j; }
        if (d2 < bd2) { bd2 = d2; bj2 = j; }
        if (d3 < bd3) { bd3 = d3; bj3 = j; }
    }

    unsigned long long key;
    {
        unsigned i0 = (unsigned)(4 * (lane + 64 * bj0) + 0);
        unsigned i1 = (unsigned)(4 * (lane + 64 * bj1) + 1);
        unsigned i2 = (unsigned)(4 * (lane + 64 * bj2) + 2);
        unsigned i3 = (unsigned)(4 * (lane + 64 * bj3) + 3);
        unsigned long long k0 = ((unsigned long long)__float_as_uint(bd0) << 32) | i0;
        unsigned long long k1 = ((unsigned long long)__float_as_uint(bd1) << 32) | i1;
        unsigned long long k2 = ((unsigned long long)__float_as_uint(bd2) << 32) | i2;
        unsigned long long k3 = ((unsigned long long)__float_as_uint(bd3) << 32) | i3;
        key = k0 < k1 ? k0 : k1;
        unsigned long long k23 = k2 < k3 ? k2 : k3;
        key = key < k23 ? key : k23;
    }

    for (int i = J * 256 + lane; i < N; i += 64) {
        float d = fabsf(pts[i] - xq);
        unsigned long long k = ((unsigned long long)__float_as_uint(d) << 32) | (unsigned)i;
        key = key < k ? key : k;
    }

    #pragma unroll
    for (int off = 1; off < 64; off <<= 1) {
        unsigned long long o = __shfl_xor(key, off, 64);
        key = key < o ? key : o;
    }

    if (lane == 0) {
        out[q] = acc[(unsigned)(key & 0xffffffffULL)];
    }
}

extern "C" void kernel_launch(void* const* d_in, const int* in_sizes, int n_in,
                              void* d_out, int out_size, void* d_ws, size_t ws_size,
                              hipStream_t stream) {
    const float* x   = (const float*)d_in[0];
    const float* pts = (const float*)d_in[1];
    const float* acc = (const float*)d_in[2];
    float* out = (float*)d_out;
    const int B = in_sizes[0];
    const int N = in_sizes[1];

    const int nchunk = N / CHUNK;
    const int nqw    = B >> 6;                       // query-waves
    const size_t need = (size_t)nchunk * (size_t)B * 8;

    const bool pow2 = (nqw > 0) && ((nqw & (nqw - 1)) == 0);
    const bool fast = (N % CHUNK == 0) && (B % 64 == 0) && pow2 &&
                      d_ws != nullptr && ws_size >= need;

    if (fast) {
        int qw_shift = 0;
        while ((1 << qw_shift) < nqw) ++qw_shift;
        const int waves  = nchunk * nqw;             // 4096 for B=4096,N=65536
        const int blocks = waves / 4;
        hipLaunchKernelGGL(nn_part_kernel, dim3(blocks), dim3(256), 0, stream,
                           x, pts, (unsigned long long*)d_ws, B, qw_shift);
        hipLaunchKernelGGL(nn_reduce_kernel, dim3((B + 3) / 4), dim3(256), 0, stream,
                           (const unsigned long long*)d_ws, acc, out, B, nchunk);
    } else {
        const int blocks = (B + QB - 1) / QB;
        hipLaunchKernelGGL(nn_kernel, dim3(blocks), dim3(256), 0, stream,
                           x, pts, acc, out, B, N);
    }
}

// Round 3
// 76.023 us; speedup vs baseline: 1.3317x; 1.3317x over previous
//
#include <hip/hip_runtime.h>

#define QB 4  // fallback: queries per block

// ---------------------------------------------------------------------------
// Kernel 1: one query per LANE, points streamed through SGPRs (wave-uniform).
// Distance-only min via v_min3 (abs = free input modifier), NO per-point index
// tracking. Track only which 16-point group last strictly lowered the min:
// that is exactly the FIRST group containing the final min value (min can
// only strictly decrease; equal values never update). Epilogue rescans the
// winning 16 points (per-lane vector loads) descending, keeping the smallest
// index whose recomputed distance is bit-identical to the min (same
// instruction sequence both passes -> identical bits).
// Writes packed (dist_bits<<32 | global_idx): u64-min across chunks preserves
// numpy first-index tie-break (dist >= 0 -> f32 bits monotone; idx ascending).
// ---------------------------------------------------------------------------
template<int CHUNK>
__global__ __launch_bounds__(256, 4)
void nn_part_kernel(const float* __restrict__ x,
                    const float* __restrict__ pts,
                    unsigned long long* __restrict__ part, // [nchunk][B]
                    int B, int qw_shift)
{
    const int lane = threadIdx.x & 63;
    // readfirstlane keeps the chunk pointer provably wave-uniform -> s_load_*
    const int wv = __builtin_amdgcn_readfirstlane((int)(threadIdx.x >> 6));
    const int w  = blockIdx.x * 4 + wv;
    const int qw = w & ((1 << qw_shift) - 1);   // query-wave index (pow2)
    const int ck = w >> qw_shift;               // point-chunk index

    const int q = (qw << 6) + lane;
    const float xq = x[q];

    const float* __restrict__ pc = pts + (size_t)ck * CHUNK;  // uniform

    const float inf = __builtin_inff();
    float bdA = inf, bdB = inf;      // two independent min chains (ILP)
    float prev = inf;
    int grp = 0;

    #pragma unroll 4
    for (int g = 0; g < CHUNK / 16; ++g) {
        #pragma unroll
        for (int t = 0; t < 4; ++t) {
            float p0 = pc[16 * g + 4 * t + 0];
            float p1 = pc[16 * g + 4 * t + 1];
            float p2 = pc[16 * g + 4 * t + 2];
            float p3 = pc[16 * g + 4 * t + 3];
            float a0 = fabsf(p0 - xq);
            float a1 = fabsf(p1 - xq);
            float a2 = fabsf(p2 - xq);
            float a3 = fabsf(p3 - xq);
            bdA = fminf(fminf(a0, a1), bdA);   // -> v_min3_f32 with |mods|
            bdB = fminf(fminf(a2, a3), bdB);   // -> v_min3_f32 with |mods|
        }
        float cur = fminf(bdA, bdB);
        grp = (cur < prev) ? g : grp;          // v_cmp + v_cndmask per 16 pts
        prev = cur;
    }

    const float bd = prev;   // == fminf(bdA,bdB) after last group

    // Epilogue: first index within winning group with dist bit-equal to bd.
    const float4* __restrict__ pg =
        reinterpret_cast<const float4*>(pc + grp * 16);
    int best = 0;
    #pragma unroll
    for (int v = 3; v >= 0; --v) {     // descending -> smallest index wins
        float4 f = pg[v];
        best = (fabsf(f.w - xq) == bd) ? 4 * v + 3 : best;
        best = (fabsf(f.z - xq) == bd) ? 4 * v + 2 : best;
        best = (fabsf(f.y - xq) == bd) ? 4 * v + 1 : best;
        best = (fabsf(f.x - xq) == bd) ? 4 * v + 0 : best;
    }

    const unsigned gidx = (unsigned)(ck * CHUNK + grp * 16 + best);
    const unsigned long long key =
        ((unsigned long long)__float_as_uint(bd) << 32) | gidx;
    part[(size_t)ck * B + q] = key;   // lane-contiguous -> coalesced
}

// ---------------------------------------------------------------------------
// Kernel 2: one wave per query u64-min-reduces nchunk partials, gathers acc.
// ---------------------------------------------------------------------------
__global__ __launch_bounds__(256, 4)
void nn_reduce_kernel(const unsigned long long* __restrict__ part,
                      const float* __restrict__ acc,
                      float* __restrict__ out,
                      int B, int nchunk)
{
    const int lane = threadIdx.x & 63;
    const int wv   = threadIdx.x >> 6;
    const int q    = blockIdx.x * 4 + wv;
    if (q >= B) return;

    unsigned long long key = ~0ULL;
    for (int c = lane; c < nchunk; c += 64) {
        unsigned long long k = part[(size_t)c * B + q];
        key = k < key ? k : key;
    }
    #pragma unroll
    for (int off = 1; off < 64; off <<= 1) {
        unsigned long long o = __shfl_xor(key, off, 64);
        key = key < o ? key : o;
    }
    if (lane == 0) {
        out[q] = acc[(unsigned)(key & 0xffffffffULL)];
    }
}

// ---------------------------------------------------------------------------
// Fallback (round-1 kernel): one query per wave, vector loads.
// ---------------------------------------------------------------------------
__global__ __launch_bounds__(256, 4)
void nn_kernel(const float* __restrict__ x,
               const float* __restrict__ pts,
               const float* __restrict__ acc,
               float* __restrict__ out,
               int B, int N) {
    const int lane = threadIdx.x & 63;
    const int wave = threadIdx.x >> 6;
    const int q    = blockIdx.x * QB + wave;
    if (q >= B) return;

    const float xq = x[q];
    const int G = N >> 2;
    const int J = G >> 6;

    float bd0 = __builtin_inff(), bd1 = __builtin_inff(),
          bd2 = __builtin_inff(), bd3 = __builtin_inff();
    int   bj0 = 0, bj1 = 0, bj2 = 0, bj3 = 0;

    const float4* __restrict__ p4 = reinterpret_cast<const float4*>(pts);

    #pragma unroll 4
    for (int j = 0; j < J; ++j) {
        float4 v = p4[lane + 64 * j];
        float d0 = fabsf(v.x - xq);
        float d1 = fabsf(v.y - xq);
        float d2 = fabsf(v.z - xq);
        float d3 = fabsf(v.w - xq);
        if (d0 < bd0) { bd0 = d0; bj0 = j; }
        if (d1 < bd1) { bd1 = d1; bj1 = j; }
        if (d2 < bd2) { bd2 = d2; bj2 = j; }
        if (d3 < bd3) { bd3 = d3; bj3 = j; }
    }

    unsigned long long key;
    {
        unsigned i0 = (unsigned)(4 * (lane + 64 * bj0) + 0);
        unsigned i1 = (unsigned)(4 * (lane + 64 * bj1) + 1);
        unsigned i2 = (unsigned)(4 * (lane + 64 * bj2) + 2);
        unsigned i3 = (unsigned)(4 * (lane + 64 * bj3) + 3);
        unsigned long long k0 = ((unsigned long long)__float_as_uint(bd0) << 32) | i0;
        unsigned long long k1 = ((unsigned long long)__float_as_uint(bd1) << 32) | i1;
        unsigned long long k2 = ((unsigned long long)__float_as_uint(bd2) << 32) | i2;
        unsigned long long k3 = ((unsigned long long)__float_as_uint(bd3) << 32) | i3;
        key = k0 < k1 ? k0 : k1;
        unsigned long long k23 = k2 < k3 ? k2 : k3;
        key = key < k23 ? key : k23;
    }

    for (int i = J * 256 + lane; i < N; i += 64) {
        float d = fabsf(pts[i] - xq);
        unsigned long long k = ((unsigned long long)__float_as_uint(d) << 32) | (unsigned)i;
        key = key < k ? key : k;
    }

    #pragma unroll
    for (int off = 1; off < 64; off <<= 1) {
        unsigned long long o = __shfl_xor(key, off, 64);
        key = key < o ? key : o;
    }

    if (lane == 0) {
        out[q] = acc[(unsigned)(key & 0xffffffffULL)];
    }
}

extern "C" void kernel_launch(void* const* d_in, const int* in_sizes, int n_in,
                              void* d_out, int out_size, void* d_ws, size_t ws_size,
                              hipStream_t stream) {
    const float* x   = (const float*)d_in[0];
    const float* pts = (const float*)d_in[1];
    const float* acc = (const float*)d_in[2];
    float* out = (float*)d_out;
    const int B = in_sizes[0];
    const int N = in_sizes[1];

    const int nqw = B >> 6;                          // query-waves
    const bool pow2 = (nqw > 0) && ((nqw & (nqw - 1)) == 0);

    int qw_shift = 0;
    while ((1 << qw_shift) < nqw) ++qw_shift;

    // Prefer CHUNK=512 (8 waves/SIMD for latency hiding) if workspace allows.
    const size_t need512  = (size_t)(N / 512)  * (size_t)B * 8;
    const size_t need1024 = (size_t)(N / 1024) * (size_t)B * 8;
    const bool ok_base = pow2 && (B % 64 == 0) && d_ws != nullptr;

    if (ok_base && (N % 512 == 0) && ws_size >= need512) {
        const int nchunk = N / 512;
        const int blocks = (nchunk * nqw) / 4;
        hipLaunchKernelGGL((nn_part_kernel<512>), dim3(blocks), dim3(256), 0,
                           stream, x, pts, (unsigned long long*)d_ws, B, qw_shift);
        hipLaunchKernelGGL(nn_reduce_kernel, dim3((B + 3) / 4), dim3(256), 0,
                           stream, (const unsigned long long*)d_ws, acc, out, B, nchunk);
    } else if (ok_base && (N % 1024 == 0) && ws_size >= need1024) {
        const int nchunk = N / 1024;
        const int blocks = (nchunk * nqw) / 4;
        hipLaunchKernelGGL((nn_part_kernel<1024>), dim3(blocks), dim3(256), 0,
                           stream, x, pts, (unsigned long long*)d_ws, B, qw_shift);
        hipLaunchKernelGGL(nn_reduce_kernel, dim3((B + 3) / 4), dim3(256), 0,
                           stream, (const unsigned long long*)d_ws, acc, out, B, nchunk);
    } else {
        const int blocks = (B + QB - 1) / QB;
        hipLaunchKernelGGL(nn_kernel, dim3(blocks), dim3(256), 0, stream,
                           x, pts, acc, out, B, N);
    }
}

// Round 4
// 71.784 us; speedup vs baseline: 1.4104x; 1.0591x over previous
//
#include <hip/hip_runtime.h>

#define CHUNK 512   // points per block (staged in LDS), 2 KB
#define GRP   32    // group-tracking granularity
#define QB    4     // fallback: queries per block

// ---------------------------------------------------------------------------
// init: best[q] = ~0 (workspace is poisoned 0xAA by the harness every call)
// ---------------------------------------------------------------------------
__global__ __launch_bounds__(256, 8)
void nn_init_kernel(unsigned long long* __restrict__ best, int B) {
    int i = blockIdx.x * 256 + threadIdx.x;
    if (i < B) best[i] = ~0ULL;
}

// ---------------------------------------------------------------------------
// main: one query per LANE; block stages a 512-pt chunk in LDS; all 4 waves
// (256 queries) scan it via broadcast ds_read_b128 (4 points/instr to all 64
// lanes — the highest pair-input delivery rate of any pipe).
// Distance-only min (v_sub + v_min3 with |abs| input modifiers, ~1.6 VALU/pt),
// NO per-point index tracking. grp = last group that strictly lowered the
// running min == FIRST group containing the final min (min only strictly
// decreases; ties never update). Epilogue rescans the winning 32 points
// descending, keeping the smallest index whose recomputed distance is
// bit-identical (identical sub+abs sequence -> identical bits).
// Cross-chunk merge: atomicMin on u64 (dist_bits<<32 | global_idx) —
// associative/commutative -> deterministic; preserves numpy first-index
// tie-break (dist >= 0 so f32 bits are monotone; idx ascending).
// ---------------------------------------------------------------------------
__global__ __launch_bounds__(256, 8)
void nn_main_kernel(const float* __restrict__ x,
                    const float* __restrict__ pts,
                    unsigned long long* __restrict__ best,
                    int qg_shift)    // nqg = B/256 (pow2)
{
    __shared__ float lds[CHUNK];
    const int tid = threadIdx.x;
    const int nqg_mask = (1 << qg_shift) - 1;
    const int qg = blockIdx.x & nqg_mask;        // query-group (256 queries)
    const int ck = blockIdx.x >> qg_shift;       // chunk index

    // stage chunk: 256 threads x float2 = 512 floats, coalesced
    reinterpret_cast<float2*>(lds)[tid] =
        reinterpret_cast<const float2*>(pts)[ck * (CHUNK / 2) + tid];
    __syncthreads();

    const int lane = tid & 63;
    const int wv   = tid >> 6;
    const int q    = (qg << 8) + (wv << 6) + lane;
    const float xq = x[q];

    const float inf = __builtin_inff();
    float bdA = inf, bdB = inf, prev = inf;
    int grp = 0;

    const float4* __restrict__ l4 = reinterpret_cast<const float4*>(lds);

    #pragma unroll 2
    for (int g = 0; g < CHUNK / GRP; ++g) {
        #pragma unroll
        for (int t = 0; t < GRP / 4; ++t) {
            float4 v = l4[g * (GRP / 4) + t];    // uniform addr -> broadcast
            float d0 = v.x - xq;
            float d1 = v.y - xq;
            float d2 = v.z - xq;
            float d3 = v.w - xq;
            bdA = fminf(fminf(fabsf(d0), fabsf(d1)), bdA);  // v_min3 |mods|
            bdB = fminf(fminf(fabsf(d2), fabsf(d3)), bdB);  // v_min3 |mods|
        }
        float cur = fminf(bdA, bdB);
        grp  = (cur < prev) ? g : grp;           // 3 VALU per 32 points
        prev = cur;
    }

    const float bd = prev;

    // Epilogue: first index in winning group with dist bit-equal to bd.
    // Per-lane LDS gather (grp differs per lane) — once per wave, cheap.
    int bi = 0;
    #pragma unroll
    for (int t = GRP / 4 - 1; t >= 0; --t) {     // descending -> first wins
        float4 v = l4[grp * (GRP / 4) + t];
        bi = (fabsf(v.w - xq) == bd) ? 4 * t + 3 : bi;
        bi = (fabsf(v.z - xq) == bd) ? 4 * t + 2 : bi;
        bi = (fabsf(v.y - xq) == bd) ? 4 * t + 1 : bi;
        bi = (fabsf(v.x - xq) == bd) ? 4 * t + 0 : bi;
    }

    const unsigned gidx = (unsigned)(ck * CHUNK + grp * GRP + bi);
    const unsigned long long key =
        ((unsigned long long)__float_as_uint(bd) << 32) | gidx;
    atomicMin(&best[q], key);
}

// ---------------------------------------------------------------------------
// gather: out[q] = acc[idx(best[q])]
// ---------------------------------------------------------------------------
__global__ __launch_bounds__(256, 8)
void nn_gather_kernel(const unsigned long long* __restrict__ best,
                      const float* __restrict__ acc,
                      float* __restrict__ out, int B) {
    int i = blockIdx.x * 256 + threadIdx.x;
    if (i < B) out[i] = acc[(unsigned)(best[i] & 0xffffffffULL)];
}

// ---------------------------------------------------------------------------
// Fallback (round-1 kernel): one query per wave, vector loads. Generic.
// ---------------------------------------------------------------------------
__global__ __launch_bounds__(256, 4)
void nn_kernel(const float* __restrict__ x,
               const float* __restrict__ pts,
               const float* __restrict__ acc,
               float* __restrict__ out,
               int B, int N) {
    const int lane = threadIdx.x & 63;
    const int wave = threadIdx.x >> 6;
    const int q    = blockIdx.x * QB + wave;
    if (q >= B) return;

    const float xq = x[q];
    const int G = N >> 2;
    const int J = G >> 6;

    float bd0 = __builtin_inff(), bd1 = __builtin_inff(),
          bd2 = __builtin_inff(), bd3 = __builtin_inff();
    int   bj0 = 0, bj1 = 0, bj2 = 0, bj3 = 0;

    const float4* __restrict__ p4 = reinterpret_cast<const float4*>(pts);

    #pragma unroll 4
    for (int j = 0; j < J; ++j) {
        float4 v = p4[lane + 64 * j];
        float d0 = fabsf(v.x - xq);
        float d1 = fabsf(v.y - xq);
        float d2 = fabsf(v.z - xq);
        float d3 = fabsf(v.w - xq);
        if (d0 < bd0) { bd0 = d0; bj0 = j; }
        if (d1 < bd1) { bd1 = d1; bj1 = j; }
        if (d2 < bd2) { bd2 = d2; bj2 = j; }
        if (d3 < bd3) { bd3 = d3; bj3 = j; }
    }

    unsigned long long key;
    {
        unsigned i0 = (unsigned)(4 * (lane + 64 * bj0) + 0);
        unsigned i1 = (unsigned)(4 * (lane + 64 * bj1) + 1);
        unsigned i2 = (unsigned)(4 * (lane + 64 * bj2) + 2);
        unsigned i3 = (unsigned)(4 * (lane + 64 * bj3) + 3);
        unsigned long long k0 = ((unsigned long long)__float_as_uint(bd0) << 32) | i0;
        unsigned long long k1 = ((unsigned long long)__float_as_uint(bd1) << 32) | i1;
        unsigned long long k2 = ((unsigned long long)__float_as_uint(bd2) << 32) | i2;
        unsigned long long k3 = ((unsigned long long)__float_as_uint(bd3) << 32) | i3;
        key = k0 < k1 ? k0 : k1;
        unsigned long long k23 = k2 < k3 ? k2 : k3;
        key = key < k23 ? key : k23;
    }

    for (int i = J * 256 + lane; i < N; i += 64) {
        float d = fabsf(pts[i] - xq);
        unsigned long long k = ((unsigned long long)__float_as_uint(d) << 32) | (unsigned)i;
        key = key < k ? key : k;
    }

    #pragma unroll
    for (int off = 1; off < 64; off <<= 1) {
        unsigned long long o = __shfl_xor(key, off, 64);
        key = key < o ? key : o;
    }

    if (lane == 0) {
        out[q] = acc[(unsigned)(key & 0xffffffffULL)];
    }
}

extern "C" void kernel_launch(void* const* d_in, const int* in_sizes, int n_in,
                              void* d_out, int out_size, void* d_ws, size_t ws_size,
                              hipStream_t stream) {
    const float* x   = (const float*)d_in[0];
    const float* pts = (const float*)d_in[1];
    const float* acc = (const float*)d_in[2];
    float* out = (float*)d_out;
    const int B = in_sizes[0];
    const int N = in_sizes[1];

    const int nqg = B >> 8;                      // query groups of 256
    const bool pow2 = (nqg > 0) && ((nqg & (nqg - 1)) == 0);
    const bool fast = pow2 && (B % 256 == 0) && (N % CHUNK == 0) &&
                      d_ws != nullptr && ws_size >= (size_t)B * 8;

    if (fast) {
        int qg_shift = 0;
        while ((1 << qg_shift) < nqg) ++qg_shift;
        const int nchunk = N / CHUNK;
        unsigned long long* best = (unsigned long long*)d_ws;

        hipLaunchKernelGGL(nn_init_kernel, dim3(nqg), dim3(256), 0, stream,
                           best, B);
        hipLaunchKernelGGL(nn_main_kernel, dim3(nchunk * nqg), dim3(256), 0,
                           stream, x, pts, best, qg_shift);
        hipLaunchKernelGGL(nn_gather_kernel, dim3(nqg), dim3(256), 0, stream,
                           best, acc, out, B);
    } else {
        const int blocks = (B + QB - 1) / QB;
        hipLaunchKernelGGL(nn_kernel, dim3(blocks), dim3(256), 0, stream,
                           x, pts, acc, out, B, N);
    }
}